// Round 4
// baseline (715.404 us; speedup 1.0000x reference)
//
#include <hip/hip_runtime.h>
#include <math.h>

// ---------------------------------------------------------------------------
// StatusGCN restructured:
//   h0 = fp8e4m3(x @ W1)              (MFMA, fp32 A cast in staging) [N,256]
//   h1 = bf16(relu(spmm(h0) + b1))                                  [N,256]
//   g3 = bf16(h1 @ (W2@W3))           (MFMA)                        [N,64]
//   t1 = bf16(spmm(g3)); degw = rowsum(w)                           [N,64]
//   out = log_softmax(spmm(t1) + degw*(b2@W3) + r)                  [N,64] f32
// Identities: spmm(X)@W == spmm(X@W);  spmm(X + 1*c) == spmm(X) + degw*c.
// CSR build: 2-phase bucket sort (pass1 LDS tile-sort -> bucket regions;
// pass2 per-bucket LDS histogram+scan writes rp and places exactly).
// r7 post-mortem: removing 3.2M per-node far-atomics: 849->729us. Confirmed.
// r8 post-mortem: 4x MLP in spmm256: 153->126us, BW 2.75->3.34 TB/s.
// r9 post-mortem (REGRESSION, reverted): 1024-thread blocks collapsed
// occupancy 67->37% (16-wave workgroups are all-or-nothing residency);
// LDS ep staging put a serialized ds_read in front of every row gather
// (the sequential ep stream was already L1-resident with deep vmcnt
// pipelining). spmm256 126->148us. KEPT from r9: packed f32x2 v_pk_fma
// (24->16 VALU ops/16B) -- it cut spmm64_a/b by ~19us combined.
// r10 (this round): r8 structure (4-wave blocks, direct ep) + pk_fma
// everywhere + spmm256 edge unroll 4->8 (32 edges/wave in flight = one
// average degree, 128B/lane outstanding).
// NOTE (r4 post-mortem): keep per-wave MFMA tile at 64x64 (acc[4][4]=64 AGPR).
// acc[4][8] put wave reg total >256 on the unified VGPR/AGPR file -> 1
// wave/SIMD -> 9.5% occupancy. Widen the BLOCK (more waves), never the wave.
// ---------------------------------------------------------------------------

typedef __bf16 bf16x8 __attribute__((ext_vector_type(8)));
typedef __bf16 bf16x4 __attribute__((ext_vector_type(4)));
typedef float f32x4 __attribute__((ext_vector_type(4)));
typedef float f32x2 __attribute__((ext_vector_type(2)));

// ---------------- CSR construction (bucketed 2-phase) ----------------

#define TILE 2048

// pass 1: tile-sorted scatter into per-bucket regions (no per-node atomics)
__global__ __launch_bounds__(1024) void bucket_scatter(const int* __restrict__ src,
                                                       const int* __restrict__ dst,
                                                       const float* __restrict__ ew,
                                                       int* __restrict__ gcnt,
                                                       int2* __restrict__ tb,
                                                       int E, int buckcap) {
    __shared__ int hist[256];
    __shared__ int hscan[256];
    __shared__ int gbase[256];
    __shared__ int2 stage[TILE];
    __shared__ unsigned char sbuck[TILE];
    int tid = threadIdx.x;
    int e0 = blockIdx.x * TILE;
    int tilecnt = min(TILE, E - e0);
    if (tid < 256) hist[tid] = 0;
    __syncthreads();
    int myb[2], myr[2], key[2], mw[2];
#pragma unroll
    for (int u = 0; u < 2; ++u) {
        int e = e0 + u * 1024 + tid;
        myb[u] = -1;
        if (e < E) {
            int d = dst[e];
            int b = d >> 9;
            key[u] = (src[e] << 9) | (d & 511);
            mw[u] = __float_as_int(ew[e]);
            myb[u] = b;
            myr[u] = atomicAdd(&hist[b], 1);   // rank within (tile, bucket)
        }
    }
    __syncthreads();
    if (tid < 256) {
        hscan[tid] = hist[tid];
        gbase[tid] = (hist[tid] > 0) ? atomicAdd(&gcnt[tid], hist[tid]) : 0;
    }
    __syncthreads();
    for (int off = 1; off < 256; off <<= 1) {    // inclusive scan of hist
        int t = 0;
        if (tid < 256 && tid >= off) t = hscan[tid - off];
        __syncthreads();
        if (tid < 256) hscan[tid] += t;
        __syncthreads();
    }
#pragma unroll
    for (int u = 0; u < 2; ++u) {
        if (myb[u] >= 0) {
            int b = myb[u];
            int p = hscan[b] - hist[b] + myr[u];
            stage[p] = make_int2(key[u], mw[u]);
            sbuck[p] = (unsigned char)b;
        }
    }
    __syncthreads();
    for (int i = tid; i < tilecnt; i += 1024) {  // bursty, run-contiguous writes
        int2 ent = stage[i];
        int b = sbuck[i];
        int exc = hscan[b] - hist[b];
        tb[(size_t)b * buckcap + gbase[b] + (i - exc)] = ent;
    }
}

// exclusive scan of the 256 bucket totals -> bucket base offsets; rp[N]=E
__global__ __launch_bounds__(256) void gscan(const int* __restrict__ gcnt,
                                             int* __restrict__ boff,
                                             int* __restrict__ rp, int N, int E) {
    __shared__ int sd[256];
    int tid = threadIdx.x;
    int v = gcnt[tid];
    sd[tid] = v;
    __syncthreads();
    for (int off = 1; off < 256; off <<= 1) {
        int t = (tid >= off) ? sd[tid - off] : 0;
        __syncthreads();
        sd[tid] += t;
        __syncthreads();
    }
    boff[tid] = sd[tid] - v;
    if (tid == 0) rp[N] = E;
}

// pass 2: LDS histogram + scan -> per-node degrees, rp, and exact placement
__global__ __launch_bounds__(1024) void bucket_place(const int2* __restrict__ tb,
                                                     const int* __restrict__ gcnt,
                                                     const int* __restrict__ boff,
                                                     int* __restrict__ rp,
                                                     int2* __restrict__ ep,
                                                     int N, int buckcap) {
    __shared__ int h[512];
    __shared__ int cursor[512];
    int b = blockIdx.x;
    int base = b << 9;
    int nn = min(512, N - base);
    int tid = threadIdx.x;
    if (tid < 512) h[tid] = 0;
    __syncthreads();
    int cb = gcnt[b];
    const int2* tbb = tb + (size_t)b * buckcap;
    for (int i = tid; i < cb; i += 1024)
        atomicAdd(&h[((unsigned)tbb[i].x) & 511], 1);
    __syncthreads();
    if (tid < 512) cursor[tid] = h[tid];
    __syncthreads();
    for (int off = 1; off < 512; off <<= 1) {    // inclusive scan
        int t = (tid < 512 && tid >= off) ? cursor[tid - off] : 0;
        __syncthreads();
        if (tid < 512) cursor[tid] += t;
        __syncthreads();
    }
    int bo = boff[b];
    if (tid < 512) {
        int excl = cursor[tid] - h[tid] + bo;    // exclusive + bucket base
        cursor[tid] = excl;
        if (tid < nn) rp[base + tid] = excl;
    }
    __syncthreads();
    for (int i = tid; i < cb; i += 1024) {       // 2nd pass: L2-warm region
        int2 e = tbb[i];
        int pos = atomicAdd(&cursor[((unsigned)e.x) & 511], 1);
        ep[pos] = make_int2((int)(((unsigned)e.x) >> 9), e.y);
    }
}

// ---------------- tiny precomputes ----------------

__global__ __launch_bounds__(256) void cast_transpose(const float* __restrict__ W,
                                                      __bf16* __restrict__ WT,
                                                      int K, int Nn) {
    int i = blockIdx.x * 256 + threadIdx.x;
    if (i < K * Nn) {
        int k = i / Nn, n = i % Nn;
        WT[(size_t)n * K + k] = (__bf16)W[i];
    }
}

__global__ __launch_bounds__(256) void make_w23t(const float* __restrict__ W2,
                                                 const float* __restrict__ W3,
                                                 __bf16* __restrict__ W23T) {
    int idx = blockIdx.x * 256 + threadIdx.x;
    int n = idx & 63, k = idx >> 6;
    float s = 0.f;
    for (int j = 0; j < 64; ++j) s = fmaf(W2[k * 64 + j], W3[j * 64 + n], s);
    W23T[n * 256 + k] = (__bf16)s;
}

__global__ void make_c(const float* __restrict__ b2, const float* __restrict__ W3,
                       float* __restrict__ c) {
    int n = threadIdx.x;
    float s = 0.f;
    for (int j = 0; j < 64; ++j) s = fmaf(b2[j], W3[j * 64 + n], s);
    c[n] = s;
}

// ------- MFMA GEMM 1: h0_fp8[M,256] = bf16(A_f32[M,512]) @ W1[512,256] ------

__global__ __launch_bounds__(512) void gemm1_fused(const float* __restrict__ A,
                                                   const __bf16* __restrict__ BT,
                                                   unsigned char* __restrict__ C, int M) {
    const int K = 512;
    __shared__ __align__(16) __bf16 As[128 * 40];
    __shared__ __align__(16) __bf16 Bs[256 * 40];
    const int tid = threadIdx.x;
    const int wave = tid >> 6, lane = tid & 63;
    const int wm = wave >> 2, wn = wave & 3;
    const int quad = lane >> 4, l16 = lane & 15;
    const int bm = blockIdx.x * 128;
    f32x4 acc[4][4] = {};
    for (int k0 = 0; k0 < K; k0 += 32) {
#pragma unroll
        for (int it = 0; it < 2; ++it) {
            int idx = tid + it * 512;
            int row = idx >> 3, ch = idx & 7;
            int gm = bm + row;
            float4 v = (gm < M) ? *(const float4*)(A + (size_t)gm * K + k0 + ch * 4)
                                : make_float4(0.f, 0.f, 0.f, 0.f);
            bf16x4 o;
            o[0] = (__bf16)v.x; o[1] = (__bf16)v.y; o[2] = (__bf16)v.z; o[3] = (__bf16)v.w;
            *(bf16x4*)(As + row * 40 + ch * 4) = o;
        }
#pragma unroll
        for (int it = 0; it < 2; ++it) {
            int idx = tid + it * 512;
            int row = idx >> 2, ch = idx & 3;
            *(bf16x8*)(Bs + row * 40 + ch * 8) =
                *(const bf16x8*)(BT + (size_t)row * K + k0 + ch * 8);
        }
        __syncthreads();
        bf16x8 a[4], b[4];
#pragma unroll
        for (int i = 0; i < 4; ++i)
            a[i] = *(bf16x8*)(As + (wm * 64 + i * 16 + l16) * 40 + quad * 8);
#pragma unroll
        for (int j = 0; j < 4; ++j)
            b[j] = *(bf16x8*)(Bs + (wn * 64 + j * 16 + l16) * 40 + quad * 8);
#pragma unroll
        for (int i = 0; i < 4; ++i)
#pragma unroll
            for (int j = 0; j < 4; ++j)
                acc[i][j] = __builtin_amdgcn_mfma_f32_16x16x32_bf16(a[i], b[j], acc[i][j], 0, 0, 0);
        __syncthreads();
    }
#pragma unroll
    for (int i = 0; i < 4; ++i)
#pragma unroll
        for (int j = 0; j < 4; ++j)
#pragma unroll
            for (int rr = 0; rr < 4; ++rr) {
                int row = bm + wm * 64 + i * 16 + quad * 4 + rr;
                int col = wn * 64 + j * 16 + l16;
                if (row < M) {
                    unsigned int p = __builtin_amdgcn_cvt_pk_fp8_f32(acc[i][j][rr],
                                                                     acc[i][j][rr], 0, false);
                    C[(size_t)row * 256 + col] = (unsigned char)(p & 0xff);
                }
            }
}

// ---------------- MFMA GEMM 2: C[M,64] = A[M,256] @ B[256,64] ---------------

__global__ __launch_bounds__(256) void gemm2_mfma(const __bf16* __restrict__ A,
                                                  const __bf16* __restrict__ BT,
                                                  __bf16* __restrict__ C, int M) {
    const int K = 256, Nn = 64;
    __shared__ __align__(16) __bf16 Bs[64 * 264];
    __shared__ __align__(16) __bf16 As[128 * 40];
    const int tid = threadIdx.x;
    const int wave = tid >> 6, lane = tid & 63;
    const int quad = lane >> 4, l16 = lane & 15;
    const int bm = blockIdx.x * 128;
#pragma unroll
    for (int it = 0; it < 8; ++it) {
        int e = tid + it * 256;
        int row = e >> 5, ch = e & 31;
        *(bf16x8*)(Bs + row * 264 + ch * 8) = *(const bf16x8*)(BT + row * 256 + ch * 8);
    }
    f32x4 acc[2][4] = {};
    for (int k0 = 0; k0 < K; k0 += 32) {
#pragma unroll
        for (int it = 0; it < 2; ++it) {
            int e = tid + it * 256;
            int row = e >> 2, ch = e & 3;
            int gm = bm + row;
            bf16x8 v = {};
            if (gm < M) v = *(const bf16x8*)(A + (size_t)gm * K + k0 + ch * 8);
            *(bf16x8*)(As + row * 40 + ch * 8) = v;
        }
        __syncthreads();
        bf16x8 a[2], b[4];
#pragma unroll
        for (int i = 0; i < 2; ++i)
            a[i] = *(bf16x8*)(As + (wave * 32 + i * 16 + l16) * 40 + quad * 8);
#pragma unroll
        for (int j = 0; j < 4; ++j)
            b[j] = *(bf16x8*)(Bs + (j * 16 + l16) * 264 + k0 + quad * 8);
#pragma unroll
        for (int i = 0; i < 2; ++i)
#pragma unroll
            for (int j = 0; j < 4; ++j)
                acc[i][j] = __builtin_amdgcn_mfma_f32_16x16x32_bf16(a[i], b[j], acc[i][j], 0, 0, 0);
        __syncthreads();
    }
#pragma unroll
    for (int i = 0; i < 2; ++i)
#pragma unroll
        for (int j = 0; j < 4; ++j)
#pragma unroll
            for (int rr = 0; rr < 4; ++rr) {
                int row = bm + wave * 32 + i * 16 + quad * 4 + rr;
                int col = j * 16 + l16;
                if (row < M) C[(size_t)row * Nn + col] = (__bf16)acc[i][j][rr];
            }
}

// ---------------- pull-mode SpMM ----------------

// r10: 4-wave blocks, direct ep stream, 32 edges in flight (unroll 8),
// packed f32x2 FMA. 16 lanes x uint4 = coalesced 256B row per edge-group.
__global__ __launch_bounds__(256) void spmm256_fp8(const unsigned char* __restrict__ h,
                                                   const int* __restrict__ rp,
                                                   const int2* __restrict__ ep,
                                                   const float* __restrict__ bias,
                                                   __bf16* __restrict__ out, int n) {
    int node = blockIdx.x * 4 + (threadIdx.x >> 6);
    if (node >= n) return;
    int lane = threadIdx.x & 63;
    int q = lane >> 4, c = lane & 15;
    int e0 = rp[node], e1 = rp[node + 1];
    f32x2 acc2[8] = {};
    for (int e = e0; e < e1; e += 32) {
#pragma unroll
        for (int u = 0; u < 8; ++u) {
            int ee = e + u * 4 + q;
            int cl = min(ee, e1 - 1);
            int2 p = ep[cl];
            float wv = (ee < e1) ? __int_as_float(p.y) : 0.f;
            f32x2 w2 = {wv, wv};
            uint4 v = *(const uint4*)(h + (size_t)p.x * 256 + c * 16);
            f32x2 f;
            f = __builtin_amdgcn_cvt_pk_f32_fp8(v.x, false);
            acc2[0] = __builtin_elementwise_fma(w2, f, acc2[0]);
            f = __builtin_amdgcn_cvt_pk_f32_fp8(v.x, true);
            acc2[1] = __builtin_elementwise_fma(w2, f, acc2[1]);
            f = __builtin_amdgcn_cvt_pk_f32_fp8(v.y, false);
            acc2[2] = __builtin_elementwise_fma(w2, f, acc2[2]);
            f = __builtin_amdgcn_cvt_pk_f32_fp8(v.y, true);
            acc2[3] = __builtin_elementwise_fma(w2, f, acc2[3]);
            f = __builtin_amdgcn_cvt_pk_f32_fp8(v.z, false);
            acc2[4] = __builtin_elementwise_fma(w2, f, acc2[4]);
            f = __builtin_amdgcn_cvt_pk_f32_fp8(v.z, true);
            acc2[5] = __builtin_elementwise_fma(w2, f, acc2[5]);
            f = __builtin_amdgcn_cvt_pk_f32_fp8(v.w, false);
            acc2[6] = __builtin_elementwise_fma(w2, f, acc2[6]);
            f = __builtin_amdgcn_cvt_pk_f32_fp8(v.w, true);
            acc2[7] = __builtin_elementwise_fma(w2, f, acc2[7]);
        }
    }
#pragma unroll
    for (int off = 16; off <= 32; off <<= 1)
#pragma unroll
        for (int i = 0; i < 8; ++i) {
            acc2[i].x += __shfl_xor(acc2[i].x, off);
            acc2[i].y += __shfl_xor(acc2[i].y, off);
        }
    if (q == 0) {
        float4 b0 = *(const float4*)(bias + c * 16);
        float4 b1 = *(const float4*)(bias + c * 16 + 4);
        float4 b2 = *(const float4*)(bias + c * 16 + 8);
        float4 b3 = *(const float4*)(bias + c * 16 + 12);
        bf16x8 o0, o1;
        o0[0] = (__bf16)fmaxf(acc2[0].x + b0.x, 0.f);
        o0[1] = (__bf16)fmaxf(acc2[0].y + b0.y, 0.f);
        o0[2] = (__bf16)fmaxf(acc2[1].x + b0.z, 0.f);
        o0[3] = (__bf16)fmaxf(acc2[1].y + b0.w, 0.f);
        o0[4] = (__bf16)fmaxf(acc2[2].x + b1.x, 0.f);
        o0[5] = (__bf16)fmaxf(acc2[2].y + b1.y, 0.f);
        o0[6] = (__bf16)fmaxf(acc2[3].x + b1.z, 0.f);
        o0[7] = (__bf16)fmaxf(acc2[3].y + b1.w, 0.f);
        o1[0] = (__bf16)fmaxf(acc2[4].x + b2.x, 0.f);
        o1[1] = (__bf16)fmaxf(acc2[4].y + b2.y, 0.f);
        o1[2] = (__bf16)fmaxf(acc2[5].x + b2.z, 0.f);
        o1[3] = (__bf16)fmaxf(acc2[5].y + b2.w, 0.f);
        o1[4] = (__bf16)fmaxf(acc2[6].x + b3.x, 0.f);
        o1[5] = (__bf16)fmaxf(acc2[6].y + b3.y, 0.f);
        o1[6] = (__bf16)fmaxf(acc2[7].x + b3.z, 0.f);
        o1[7] = (__bf16)fmaxf(acc2[7].y + b3.w, 0.f);
        *(bf16x8*)(out + (size_t)node * 256 + c * 16) = o0;
        *(bf16x8*)(out + (size_t)node * 256 + c * 16 + 8) = o1;
    }
}

__global__ __launch_bounds__(256) void spmm64_a(const __bf16* __restrict__ h,
                                                const int* __restrict__ rp,
                                                const int2* __restrict__ ep,
                                                __bf16* __restrict__ out,
                                                float* __restrict__ degw, int n) {
    int node = blockIdx.x * 4 + (threadIdx.x >> 6);
    if (node >= n) return;
    int lane = threadIdx.x & 63;
    int g = lane >> 3, c = lane & 7;
    int e0 = rp[node], e1 = rp[node + 1];
    int deg = e1 - e0;
    f32x2 acc2[4] = {};
    float ws = 0.f;
    for (int e = 0; e < deg; e += 32) {
#pragma unroll
        for (int u = 0; u < 4; ++u) {
            int s = e + u * 8 + g;
            int k = min(s, deg - 1);
            int2 p = ep[e0 + k];
            float wv = (s < deg) ? __int_as_float(p.y) : 0.f;
            f32x2 w2 = {wv, wv};
            uint4 v = *(const uint4*)(h + (size_t)p.x * 64 + c * 8);
            f32x2 f;
            f = f32x2{__uint_as_float(v.x << 16), __uint_as_float(v.x & 0xffff0000u)};
            acc2[0] = __builtin_elementwise_fma(w2, f, acc2[0]);
            f = f32x2{__uint_as_float(v.y << 16), __uint_as_float(v.y & 0xffff0000u)};
            acc2[1] = __builtin_elementwise_fma(w2, f, acc2[1]);
            f = f32x2{__uint_as_float(v.z << 16), __uint_as_float(v.z & 0xffff0000u)};
            acc2[2] = __builtin_elementwise_fma(w2, f, acc2[2]);
            f = f32x2{__uint_as_float(v.w << 16), __uint_as_float(v.w & 0xffff0000u)};
            acc2[3] = __builtin_elementwise_fma(w2, f, acc2[3]);
            ws += wv;
        }
    }
#pragma unroll
    for (int off = 8; off <= 32; off <<= 1) {
        ws += __shfl_xor(ws, off);
#pragma unroll
        for (int i = 0; i < 4; ++i) {
            acc2[i].x += __shfl_xor(acc2[i].x, off);
            acc2[i].y += __shfl_xor(acc2[i].y, off);
        }
    }
    if (lane == 0) degw[node] = ws;
    if (g == 0) {
        bf16x8 o;
#pragma unroll
        for (int i = 0; i < 4; ++i) {
            o[2 * i] = (__bf16)acc2[i].x;
            o[2 * i + 1] = (__bf16)acc2[i].y;
        }
        *(bf16x8*)(out + (size_t)node * 64 + c * 8) = o;
    }
}

__global__ __launch_bounds__(256) void spmm64_b(const __bf16* __restrict__ h,
                                                const int* __restrict__ rp,
                                                const int2* __restrict__ ep,
                                                const float* __restrict__ degw,
                                                const float* __restrict__ cvec,
                                                const float* __restrict__ r,
                                                float* __restrict__ out, int n) {
    int node = blockIdx.x * 4 + (threadIdx.x >> 6);
    if (node >= n) return;
    int lane = threadIdx.x & 63;
    int g = lane >> 3, c = lane & 7;
    int e0 = rp[node], e1 = rp[node + 1];
    int deg = e1 - e0;
    f32x2 acc2[4] = {};
    for (int e = 0; e < deg; e += 32) {
#pragma unroll
        for (int u = 0; u < 4; ++u) {
            int s = e + u * 8 + g;
            int k = min(s, deg - 1);
            int2 p = ep[e0 + k];
            float wv = (s < deg) ? __int_as_float(p.y) : 0.f;
            f32x2 w2 = {wv, wv};
            uint4 v = *(const uint4*)(h + (size_t)p.x * 64 + c * 8);
            f32x2 f;
            f = f32x2{__uint_as_float(v.x << 16), __uint_as_float(v.x & 0xffff0000u)};
            acc2[0] = __builtin_elementwise_fma(w2, f, acc2[0]);
            f = f32x2{__uint_as_float(v.y << 16), __uint_as_float(v.y & 0xffff0000u)};
            acc2[1] = __builtin_elementwise_fma(w2, f, acc2[1]);
            f = f32x2{__uint_as_float(v.z << 16), __uint_as_float(v.z & 0xffff0000u)};
            acc2[2] = __builtin_elementwise_fma(w2, f, acc2[2]);
            f = f32x2{__uint_as_float(v.w << 16), __uint_as_float(v.w & 0xffff0000u)};
            acc2[3] = __builtin_elementwise_fma(w2, f, acc2[3]);
        }
    }
#pragma unroll
    for (int off = 8; off <= 32; off <<= 1)
#pragma unroll
        for (int i = 0; i < 4; ++i) {
            acc2[i].x += __shfl_xor(acc2[i].x, off);
            acc2[i].y += __shfl_xor(acc2[i].y, off);
        }
    float dw = degw[node];
    float4 c0 = *(const float4*)(cvec + c * 8), c1 = *(const float4*)(cvec + c * 8 + 4);
    float4 r0 = *(const float4*)(r + c * 8),    r1 = *(const float4*)(r + c * 8 + 4);
    float v[8];
    v[0] = acc2[0].x + dw * c0.x + r0.x; v[1] = acc2[0].y + dw * c0.y + r0.y;
    v[2] = acc2[1].x + dw * c0.z + r0.z; v[3] = acc2[1].y + dw * c0.w + r0.w;
    v[4] = acc2[2].x + dw * c1.x + r1.x; v[5] = acc2[2].y + dw * c1.y + r1.y;
    v[6] = acc2[3].x + dw * c1.z + r1.z; v[7] = acc2[3].y + dw * c1.w + r1.w;
    float m = v[0];
#pragma unroll
    for (int i = 1; i < 8; ++i) m = fmaxf(m, v[i]);
#pragma unroll
    for (int off = 1; off <= 4; off <<= 1) m = fmaxf(m, __shfl_xor(m, off));
    float s = 0.f;
#pragma unroll
    for (int i = 0; i < 8; ++i) s += __expf(v[i] - m);
#pragma unroll
    for (int off = 1; off <= 4; off <<= 1) s += __shfl_xor(s, off);
    float ls = m + __logf(s);
    if (g == 0) {
        float4 o0 = make_float4(v[0] - ls, v[1] - ls, v[2] - ls, v[3] - ls);
        float4 o1 = make_float4(v[4] - ls, v[5] - ls, v[6] - ls, v[7] - ls);
        *(float4*)(out + (size_t)node * 64 + c * 8) = o0;
        *(float4*)(out + (size_t)node * 64 + c * 8 + 4) = o1;
    }
}

// ---------------------------------------------------------------------------

extern "C" void kernel_launch(void* const* d_in, const int* in_sizes, int n_in,
                              void* d_out, int out_size, void* d_ws, size_t ws_size,
                              hipStream_t stream) {
    const float* x   = (const float*)d_in[0];
    const int*   src = (const int*)d_in[1];
    const int*   dst = (const int*)d_in[2];
    const float* ew  = (const float*)d_in[3];
    const float* W1  = (const float*)d_in[4];
    const float* b1  = (const float*)d_in[5];
    const float* W2  = (const float*)d_in[6];
    const float* b2  = (const float*)d_in[7];
    const float* W3  = (const float*)d_in[8];
    const float* r   = (const float*)d_in[9];

    const int N = in_sizes[0] / 512;       // 100000
    const int E = in_sizes[1];             // 3200000
    const int NB = (N + 511) >> 9;         // dst buckets (196)
    const int buckcap = (((E / NB) * 5) / 4 + 255) & ~255;   // ~20480

    // ---- workspace layout ----
    char* ws = (char*)d_ws;
    __bf16* h1 = (__bf16*)ws;                            // N*256 bf16 @ 0
    char* regB = ws + (size_t)N * 512;
    unsigned char* h0f = (unsigned char*)regB;           // N*256 fp8
    __bf16* g3   = (__bf16*)regB;                        // reuse after spmm256
    __bf16* t1   = (__bf16*)(regB + (size_t)N * 128);
    float*  degw = (float*)(regB + (size_t)N * 256);
    char* regC = regB + (size_t)N * 512;
    __bf16* W1T  = (__bf16*)regC;                        // 512*256 bf16
    __bf16* W23T = (__bf16*)(regC + 512 * 256 * 2);      // 64*256 bf16
    float*  cvec = (float*)(regC + 512 * 256 * 2 + 64 * 256 * 2);
    char* regD = regC + 512 * 1024;
    int*  rp   = (int*)regD;                             // N+1 (pad to N+2)
    int*  gcnt = rp + (N + 2);                           // 256 (zeroed)
    int*  boff = gcnt + 256;                             // 256 bucket bases
    int2* ep   = (int2*)(boff + 256);                    // E pairs (8B aligned)
    int2* tb   = ep + E;                                 // NB*buckcap entries

    // ---- CSR build (2-phase bucket sort, no per-node global atomics) ----
    hipMemsetAsync(gcnt, 0, 256 * sizeof(int), stream);
    bucket_scatter<<<(E + TILE - 1) / TILE, 1024, 0, stream>>>(src, dst, ew,
                                                               gcnt, tb, E, buckcap);
    gscan<<<1, 256, 0, stream>>>(gcnt, boff, rp, N, E);
    bucket_place<<<NB, 1024, 0, stream>>>(tb, gcnt, boff, rp, ep, N, buckcap);

    // ---- precomputes ----
    cast_transpose<<<(512 * 256 + 255) / 256, 256, 0, stream>>>(W1, W1T, 512, 256);
    make_w23t<<<64, 256, 0, stream>>>(W2, W3, W23T);
    make_c<<<1, 64, 0, stream>>>(b2, W3, cvec);

    // ---- layer 1 ----
    gemm1_fused<<<(N + 127) / 128, 512, 0, stream>>>(x, W1T, h0f, N);
    spmm256_fp8<<<(N + 3) / 4, 256, 0, stream>>>(h0f, rp, ep, b1, h1, N);

    // ---- fused layers 2+3 ----
    gemm2_mfma<<<(N + 127) / 128, 256, 0, stream>>>(h1, W23T, g3, N);
    spmm64_a<<<(N + 3) / 4, 256, 0, stream>>>(g3, rp, ep, t1, degw, N);
    spmm64_b<<<(N + 3) / 4, 256, 0, stream>>>(t1, rp, ep, degw, cvec, r, (float*)d_out, N);
}

// Round 5
// 687.019 us; speedup vs baseline: 1.0413x; 1.0413x over previous
//
#include <hip/hip_runtime.h>
#include <math.h>

// ---------------------------------------------------------------------------
// StatusGCN restructured:
//   h0 = fp8e4m3(x @ W1)              (MFMA, fp32 A cast in staging) [N,256]
//   h1 = bf16(relu(spmm(h0) + b1))                                  [N,256]
//   g3 = bf16(h1 @ (W2@W3))           (MFMA)                        [N,64]
//   t1 = bf16(spmm(g3)); degw = rowsum(w)                           [N,64]
//   out = log_softmax(spmm(t1) + degw*(b2@W3) + r)                  [N,64] f32
// Identities: spmm(X)@W == spmm(X@W);  spmm(X + 1*c) == spmm(X) + degw*c.
// CSR build: 2-phase bucket sort (pass1 LDS tile-sort -> bucket regions;
// pass2 per-bucket LDS histogram+scan writes rp and places exactly).
// r7: removed 3.2M per-node far-atomics: 849->729us.
// r8: 16-slot MLP in spmm256: 153->126us (BW 2.75->3.34 TB/s).
// r9: 1024-blocks+LDS-ep REGRESSED spmm256 (ds_read serialized the 256B
//     gather; 16-wave blocks dropped occ to 37%) but HELPED spmm64_a/b
//     (-19us: ep entry shared by 8 lanes -> LDS broadcast amortizes).
// r10: unroll 8 (stride 32 ~= mean degree) wasted ~half the slots on
//     clamped duplicates for nodes needing a 2nd iter: 126->134us. FETCH
//     pinned ~358MB across all variants -> ~3 TB/s random-256B-gather
//     ceiling confirmed; scheduling exhausted for spmm256.
// r11 (this round): recombination of proven-best forms. spmm256 = r8-exact
// (125.7us). spmm64_a/b = r9-exact (LDS-ep, 1024 threads). gscan folded
// into bucket_place (per-block redundant 256-scan); make_c folded into
// make_w23t. -2 serialized launches.
// NOTE (r4 post-mortem): keep per-wave MFMA tile at 64x64 (acc[4][4]=64 AGPR).
// Widen the BLOCK (more waves), never the wave.
// ---------------------------------------------------------------------------

typedef __bf16 bf16x8 __attribute__((ext_vector_type(8)));
typedef __bf16 bf16x4 __attribute__((ext_vector_type(4)));
typedef float f32x4 __attribute__((ext_vector_type(4)));
typedef float f32x2 __attribute__((ext_vector_type(2)));

// ---------------- CSR construction (bucketed 2-phase) ----------------

#define TILE 2048

// pass 1: tile-sorted scatter into per-bucket regions (no per-node atomics)
__global__ __launch_bounds__(1024) void bucket_scatter(const int* __restrict__ src,
                                                       const int* __restrict__ dst,
                                                       const float* __restrict__ ew,
                                                       int* __restrict__ gcnt,
                                                       int2* __restrict__ tb,
                                                       int E, int buckcap) {
    __shared__ int hist[256];
    __shared__ int hscan[256];
    __shared__ int gbase[256];
    __shared__ int2 stage[TILE];
    __shared__ unsigned char sbuck[TILE];
    int tid = threadIdx.x;
    int e0 = blockIdx.x * TILE;
    int tilecnt = min(TILE, E - e0);
    if (tid < 256) hist[tid] = 0;
    __syncthreads();
    int myb[2], myr[2], key[2], mw[2];
#pragma unroll
    for (int u = 0; u < 2; ++u) {
        int e = e0 + u * 1024 + tid;
        myb[u] = -1;
        if (e < E) {
            int d = dst[e];
            int b = d >> 9;
            key[u] = (src[e] << 9) | (d & 511);
            mw[u] = __float_as_int(ew[e]);
            myb[u] = b;
            myr[u] = atomicAdd(&hist[b], 1);   // rank within (tile, bucket)
        }
    }
    __syncthreads();
    if (tid < 256) {
        hscan[tid] = hist[tid];
        gbase[tid] = (hist[tid] > 0) ? atomicAdd(&gcnt[tid], hist[tid]) : 0;
    }
    __syncthreads();
    for (int off = 1; off < 256; off <<= 1) {    // inclusive scan of hist
        int t = 0;
        if (tid < 256 && tid >= off) t = hscan[tid - off];
        __syncthreads();
        if (tid < 256) hscan[tid] += t;
        __syncthreads();
    }
#pragma unroll
    for (int u = 0; u < 2; ++u) {
        if (myb[u] >= 0) {
            int b = myb[u];
            int p = hscan[b] - hist[b] + myr[u];
            stage[p] = make_int2(key[u], mw[u]);
            sbuck[p] = (unsigned char)b;
        }
    }
    __syncthreads();
    for (int i = tid; i < tilecnt; i += 1024) {  // bursty, run-contiguous writes
        int2 ent = stage[i];
        int b = sbuck[i];
        int exc = hscan[b] - hist[b];
        tb[(size_t)b * buckcap + gbase[b] + (i - exc)] = ent;
    }
}

// pass 2: per-block gcnt scan (folds old gscan kernel) + LDS histogram +
// scan -> per-node degrees, rp, and exact placement
__global__ __launch_bounds__(1024) void bucket_place(const int2* __restrict__ tb,
                                                     const int* __restrict__ gcnt,
                                                     int* __restrict__ rp,
                                                     int2* __restrict__ ep,
                                                     int N, int buckcap) {
    __shared__ int h[512];
    __shared__ int cursor[512];
    __shared__ int gs[256];
    int b = blockIdx.x;
    int base = b << 9;
    int nn = min(512, N - base);
    int tid = threadIdx.x;
    if (tid < 512) h[tid] = 0;
    if (tid < 256) gs[tid] = gcnt[tid];
    __syncthreads();
    for (int off = 1; off < 256; off <<= 1) {    // inclusive scan of gcnt
        int t = (tid < 256 && tid >= off) ? gs[tid - off] : 0;
        __syncthreads();
        if (tid < 256) gs[tid] += t;
        __syncthreads();
    }
    int cb = gcnt[b];
    int bo = gs[b] - cb;                          // exclusive bucket base
    if (b == 0 && tid == 0) rp[N] = gs[255];      // total = E
    const int2* tbb = tb + (size_t)b * buckcap;
    for (int i = tid; i < cb; i += 1024)
        atomicAdd(&h[((unsigned)tbb[i].x) & 511], 1);
    __syncthreads();
    if (tid < 512) cursor[tid] = h[tid];
    __syncthreads();
    for (int off = 1; off < 512; off <<= 1) {    // inclusive scan
        int t = (tid < 512 && tid >= off) ? cursor[tid - off] : 0;
        __syncthreads();
        if (tid < 512) cursor[tid] += t;
        __syncthreads();
    }
    if (tid < 512) {
        int excl = cursor[tid] - h[tid] + bo;    // exclusive + bucket base
        cursor[tid] = excl;
        if (tid < nn) rp[base + tid] = excl;
    }
    __syncthreads();
    for (int i = tid; i < cb; i += 1024) {       // 2nd pass: L2-warm region
        int2 e = tbb[i];
        int pos = atomicAdd(&cursor[((unsigned)e.x) & 511], 1);
        ep[pos] = make_int2((int)(((unsigned)e.x) >> 9), e.y);
    }
}

// ---------------- tiny precomputes ----------------

__global__ __launch_bounds__(256) void cast_transpose(const float* __restrict__ W,
                                                      __bf16* __restrict__ WT,
                                                      int K, int Nn) {
    int i = blockIdx.x * 256 + threadIdx.x;
    if (i < K * Nn) {
        int k = i / Nn, n = i % Nn;
        WT[(size_t)n * K + k] = (__bf16)W[i];
    }
}

// W23T = (W2@W3)^T  and  cvec = b2@W3  (folded make_c)
__global__ __launch_bounds__(256) void make_w23t(const float* __restrict__ W2,
                                                 const float* __restrict__ W3,
                                                 const float* __restrict__ b2,
                                                 __bf16* __restrict__ W23T,
                                                 float* __restrict__ cvec) {
    int idx = blockIdx.x * 256 + threadIdx.x;
    int n = idx & 63, k = idx >> 6;
    float s = 0.f;
    for (int j = 0; j < 64; ++j) s = fmaf(W2[k * 64 + j], W3[j * 64 + n], s);
    W23T[n * 256 + k] = (__bf16)s;
    if (idx < 64) {
        float t = 0.f;
        for (int j = 0; j < 64; ++j) t = fmaf(b2[j], W3[j * 64 + idx], t);
        cvec[idx] = t;
    }
}

// ------- MFMA GEMM 1: h0_fp8[M,256] = bf16(A_f32[M,512]) @ W1[512,256] ------

__global__ __launch_bounds__(512) void gemm1_fused(const float* __restrict__ A,
                                                   const __bf16* __restrict__ BT,
                                                   unsigned char* __restrict__ C, int M) {
    const int K = 512;
    __shared__ __align__(16) __bf16 As[128 * 40];
    __shared__ __align__(16) __bf16 Bs[256 * 40];
    const int tid = threadIdx.x;
    const int wave = tid >> 6, lane = tid & 63;
    const int wm = wave >> 2, wn = wave & 3;
    const int quad = lane >> 4, l16 = lane & 15;
    const int bm = blockIdx.x * 128;
    f32x4 acc[4][4] = {};
    for (int k0 = 0; k0 < K; k0 += 32) {
#pragma unroll
        for (int it = 0; it < 2; ++it) {
            int idx = tid + it * 512;
            int row = idx >> 3, ch = idx & 7;
            int gm = bm + row;
            float4 v = (gm < M) ? *(const float4*)(A + (size_t)gm * K + k0 + ch * 4)
                                : make_float4(0.f, 0.f, 0.f, 0.f);
            bf16x4 o;
            o[0] = (__bf16)v.x; o[1] = (__bf16)v.y; o[2] = (__bf16)v.z; o[3] = (__bf16)v.w;
            *(bf16x4*)(As + row * 40 + ch * 4) = o;
        }
#pragma unroll
        for (int it = 0; it < 2; ++it) {
            int idx = tid + it * 512;
            int row = idx >> 2, ch = idx & 3;
            *(bf16x8*)(Bs + row * 40 + ch * 8) =
                *(const bf16x8*)(BT + (size_t)row * K + k0 + ch * 8);
        }
        __syncthreads();
        bf16x8 a[4], b[4];
#pragma unroll
        for (int i = 0; i < 4; ++i)
            a[i] = *(bf16x8*)(As + (wm * 64 + i * 16 + l16) * 40 + quad * 8);
#pragma unroll
        for (int j = 0; j < 4; ++j)
            b[j] = *(bf16x8*)(Bs + (wn * 64 + j * 16 + l16) * 40 + quad * 8);
#pragma unroll
        for (int i = 0; i < 4; ++i)
#pragma unroll
            for (int j = 0; j < 4; ++j)
                acc[i][j] = __builtin_amdgcn_mfma_f32_16x16x32_bf16(a[i], b[j], acc[i][j], 0, 0, 0);
        __syncthreads();
    }
#pragma unroll
    for (int i = 0; i < 4; ++i)
#pragma unroll
        for (int j = 0; j < 4; ++j)
#pragma unroll
            for (int rr = 0; rr < 4; ++rr) {
                int row = bm + wm * 64 + i * 16 + quad * 4 + rr;
                int col = wn * 64 + j * 16 + l16;
                if (row < M) {
                    unsigned int p = __builtin_amdgcn_cvt_pk_fp8_f32(acc[i][j][rr],
                                                                     acc[i][j][rr], 0, false);
                    C[(size_t)row * 256 + col] = (unsigned char)(p & 0xff);
                }
            }
}

// ---------------- MFMA GEMM 2: C[M,64] = A[M,256] @ B[256,64] ---------------

__global__ __launch_bounds__(256) void gemm2_mfma(const __bf16* __restrict__ A,
                                                  const __bf16* __restrict__ BT,
                                                  __bf16* __restrict__ C, int M) {
    const int K = 256, Nn = 64;
    __shared__ __align__(16) __bf16 Bs[64 * 264];
    __shared__ __align__(16) __bf16 As[128 * 40];
    const int tid = threadIdx.x;
    const int wave = tid >> 6, lane = tid & 63;
    const int quad = lane >> 4, l16 = lane & 15;
    const int bm = blockIdx.x * 128;
#pragma unroll
    for (int it = 0; it < 8; ++it) {
        int e = tid + it * 256;
        int row = e >> 5, ch = e & 31;
        *(bf16x8*)(Bs + row * 264 + ch * 8) = *(const bf16x8*)(BT + row * 256 + ch * 8);
    }
    f32x4 acc[2][4] = {};
    for (int k0 = 0; k0 < K; k0 += 32) {
#pragma unroll
        for (int it = 0; it < 2; ++it) {
            int e = tid + it * 256;
            int row = e >> 2, ch = e & 3;
            int gm = bm + row;
            bf16x8 v = {};
            if (gm < M) v = *(const bf16x8*)(A + (size_t)gm * K + k0 + ch * 8);
            *(bf16x8*)(As + row * 40 + ch * 8) = v;
        }
        __syncthreads();
        bf16x8 a[2], b[4];
#pragma unroll
        for (int i = 0; i < 2; ++i)
            a[i] = *(bf16x8*)(As + (wave * 32 + i * 16 + l16) * 40 + quad * 8);
#pragma unroll
        for (int j = 0; j < 4; ++j)
            b[j] = *(bf16x8*)(Bs + (j * 16 + l16) * 264 + k0 + quad * 8);
#pragma unroll
        for (int i = 0; i < 2; ++i)
#pragma unroll
            for (int j = 0; j < 4; ++j)
                acc[i][j] = __builtin_amdgcn_mfma_f32_16x16x32_bf16(a[i], b[j], acc[i][j], 0, 0, 0);
        __syncthreads();
    }
#pragma unroll
    for (int i = 0; i < 2; ++i)
#pragma unroll
        for (int j = 0; j < 4; ++j)
#pragma unroll
            for (int rr = 0; rr < 4; ++rr) {
                int row = bm + wave * 32 + i * 16 + quad * 4 + rr;
                int col = j * 16 + l16;
                if (row < M) C[(size_t)row * Nn + col] = (__bf16)acc[i][j][rr];
            }
}

// ---------------- pull-mode SpMM ----------------

// r8-exact: 4-wave blocks, direct ep stream, 16 slots/iter (4 edges x
// unroll 4), 16 lanes x uint4 = coalesced 256B row. Proven 125.7us.
__global__ __launch_bounds__(256) void spmm256_fp8(const unsigned char* __restrict__ h,
                                                   const int* __restrict__ rp,
                                                   const int2* __restrict__ ep,
                                                   const float* __restrict__ bias,
                                                   __bf16* __restrict__ out, int n) {
    int node = blockIdx.x * 4 + (threadIdx.x >> 6);
    if (node >= n) return;
    int lane = threadIdx.x & 63;
    int q = lane >> 4, c = lane & 15;
    int e0 = rp[node], e1 = rp[node + 1];
    float acc[16] = {};
    for (int e = e0; e < e1; e += 16) {
#pragma unroll
        for (int u = 0; u < 4; ++u) {
            int ee = e + u * 4 + q;
            int cl = min(ee, e1 - 1);
            int2 p = ep[cl];
            float w = (ee < e1) ? __int_as_float(p.y) : 0.f;
            uint4 v = *(const uint4*)(h + (size_t)p.x * 256 + c * 16);
            f32x2 f;
            f = __builtin_amdgcn_cvt_pk_f32_fp8(v.x, false);
            acc[0] = fmaf(w, f.x, acc[0]);  acc[1] = fmaf(w, f.y, acc[1]);
            f = __builtin_amdgcn_cvt_pk_f32_fp8(v.x, true);
            acc[2] = fmaf(w, f.x, acc[2]);  acc[3] = fmaf(w, f.y, acc[3]);
            f = __builtin_amdgcn_cvt_pk_f32_fp8(v.y, false);
            acc[4] = fmaf(w, f.x, acc[4]);  acc[5] = fmaf(w, f.y, acc[5]);
            f = __builtin_amdgcn_cvt_pk_f32_fp8(v.y, true);
            acc[6] = fmaf(w, f.x, acc[6]);  acc[7] = fmaf(w, f.y, acc[7]);
            f = __builtin_amdgcn_cvt_pk_f32_fp8(v.z, false);
            acc[8] = fmaf(w, f.x, acc[8]);  acc[9] = fmaf(w, f.y, acc[9]);
            f = __builtin_amdgcn_cvt_pk_f32_fp8(v.z, true);
            acc[10] = fmaf(w, f.x, acc[10]); acc[11] = fmaf(w, f.y, acc[11]);
            f = __builtin_amdgcn_cvt_pk_f32_fp8(v.w, false);
            acc[12] = fmaf(w, f.x, acc[12]); acc[13] = fmaf(w, f.y, acc[13]);
            f = __builtin_amdgcn_cvt_pk_f32_fp8(v.w, true);
            acc[14] = fmaf(w, f.x, acc[14]); acc[15] = fmaf(w, f.y, acc[15]);
        }
    }
#pragma unroll
    for (int off = 16; off <= 32; off <<= 1)
#pragma unroll
        for (int i = 0; i < 16; ++i) acc[i] += __shfl_xor(acc[i], off);
    if (q == 0) {
        float4 b0 = *(const float4*)(bias + c * 16);
        float4 b1 = *(const float4*)(bias + c * 16 + 4);
        float4 b2 = *(const float4*)(bias + c * 16 + 8);
        float4 b3 = *(const float4*)(bias + c * 16 + 12);
        bf16x8 o0, o1;
        o0[0] = (__bf16)fmaxf(acc[0] + b0.x, 0.f);
        o0[1] = (__bf16)fmaxf(acc[1] + b0.y, 0.f);
        o0[2] = (__bf16)fmaxf(acc[2] + b0.z, 0.f);
        o0[3] = (__bf16)fmaxf(acc[3] + b0.w, 0.f);
        o0[4] = (__bf16)fmaxf(acc[4] + b1.x, 0.f);
        o0[5] = (__bf16)fmaxf(acc[5] + b1.y, 0.f);
        o0[6] = (__bf16)fmaxf(acc[6] + b1.z, 0.f);
        o0[7] = (__bf16)fmaxf(acc[7] + b1.w, 0.f);
        o1[0] = (__bf16)fmaxf(acc[8] + b2.x, 0.f);
        o1[1] = (__bf16)fmaxf(acc[9] + b2.y, 0.f);
        o1[2] = (__bf16)fmaxf(acc[10] + b2.z, 0.f);
        o1[3] = (__bf16)fmaxf(acc[11] + b2.w, 0.f);
        o1[4] = (__bf16)fmaxf(acc[12] + b3.x, 0.f);
        o1[5] = (__bf16)fmaxf(acc[13] + b3.y, 0.f);
        o1[6] = (__bf16)fmaxf(acc[14] + b3.z, 0.f);
        o1[7] = (__bf16)fmaxf(acc[15] + b3.w, 0.f);
        *(bf16x8*)(out + (size_t)node * 256 + c * 16) = o0;
        *(bf16x8*)(out + (size_t)node * 256 + c * 16 + 8) = o1;
    }
}

// r9-exact: 1024-thread blocks, LDS-staged ep (entry shared by 8 lanes ->
// broadcast amortizes), packed f32x2 FMA. Proven -19us vs r8 baseline.
__global__ __launch_bounds__(1024) void spmm64_a(const __bf16* __restrict__ h,
                                                 const int* __restrict__ rp,
                                                 const int2* __restrict__ ep,
                                                 __bf16* __restrict__ out,
                                                 float* __restrict__ degw, int n) {
    __shared__ int2 eps[16][128];
    int wave = threadIdx.x >> 6;
    int node = blockIdx.x * 16 + wave;
    if (node >= n) return;
    int lane = threadIdx.x & 63;
    int g = lane >> 3, c = lane & 7;
    int e0 = rp[node], e1 = rp[node + 1];
    int deg = e1 - e0;
    for (int k = lane; k < min(deg, 128); k += 64) eps[wave][k] = ep[e0 + k];
    f32x2 acc2[4] = {};
    float ws = 0.f;
    auto run = [&](auto fetch) {
        for (int e = 0; e < deg; e += 32) {
#pragma unroll
            for (int u = 0; u < 4; ++u) {
                int s = e + u * 8 + g;
                int k = min(s, deg - 1);
                int2 p = fetch(k);
                float wv = (s < deg) ? __int_as_float(p.y) : 0.f;
                f32x2 w2 = {wv, wv};
                uint4 v = *(const uint4*)(h + (size_t)p.x * 64 + c * 8);
                f32x2 f;
                f = f32x2{__uint_as_float(v.x << 16), __uint_as_float(v.x & 0xffff0000u)};
                acc2[0] = __builtin_elementwise_fma(w2, f, acc2[0]);
                f = f32x2{__uint_as_float(v.y << 16), __uint_as_float(v.y & 0xffff0000u)};
                acc2[1] = __builtin_elementwise_fma(w2, f, acc2[1]);
                f = f32x2{__uint_as_float(v.z << 16), __uint_as_float(v.z & 0xffff0000u)};
                acc2[2] = __builtin_elementwise_fma(w2, f, acc2[2]);
                f = f32x2{__uint_as_float(v.w << 16), __uint_as_float(v.w & 0xffff0000u)};
                acc2[3] = __builtin_elementwise_fma(w2, f, acc2[3]);
                ws += wv;
            }
        }
    };
    if (deg <= 128) run([&](int k) { return eps[wave][k]; });
    else           run([&](int k) { return ep[e0 + k]; });
#pragma unroll
    for (int off = 8; off <= 32; off <<= 1) {
        ws += __shfl_xor(ws, off);
#pragma unroll
        for (int i = 0; i < 4; ++i) {
            acc2[i].x += __shfl_xor(acc2[i].x, off);
            acc2[i].y += __shfl_xor(acc2[i].y, off);
        }
    }
    if (lane == 0) degw[node] = ws;
    if (g == 0) {
        bf16x8 o;
#pragma unroll
        for (int i = 0; i < 4; ++i) {
            o[2 * i] = (__bf16)acc2[i].x;
            o[2 * i + 1] = (__bf16)acc2[i].y;
        }
        *(bf16x8*)(out + (size_t)node * 64 + c * 8) = o;
    }
}

__global__ __launch_bounds__(1024) void spmm64_b(const __bf16* __restrict__ h,
                                                 const int* __restrict__ rp,
                                                 const int2* __restrict__ ep,
                                                 const float* __restrict__ degw,
                                                 const float* __restrict__ cvec,
                                                 const float* __restrict__ r,
                                                 float* __restrict__ out, int n) {
    __shared__ int2 eps[16][128];
    int wave = threadIdx.x >> 6;
    int node = blockIdx.x * 16 + wave;
    if (node >= n) return;
    int lane = threadIdx.x & 63;
    int g = lane >> 3, c = lane & 7;
    int e0 = rp[node], e1 = rp[node + 1];
    int deg = e1 - e0;
    for (int k = lane; k < min(deg, 128); k += 64) eps[wave][k] = ep[e0 + k];
    f32x2 acc2[4] = {};
    auto run = [&](auto fetch) {
        for (int e = 0; e < deg; e += 32) {
#pragma unroll
            for (int u = 0; u < 4; ++u) {
                int s = e + u * 8 + g;
                int k = min(s, deg - 1);
                int2 p = fetch(k);
                float wv = (s < deg) ? __int_as_float(p.y) : 0.f;
                f32x2 w2 = {wv, wv};
                uint4 v = *(const uint4*)(h + (size_t)p.x * 64 + c * 8);
                f32x2 f;
                f = f32x2{__uint_as_float(v.x << 16), __uint_as_float(v.x & 0xffff0000u)};
                acc2[0] = __builtin_elementwise_fma(w2, f, acc2[0]);
                f = f32x2{__uint_as_float(v.y << 16), __uint_as_float(v.y & 0xffff0000u)};
                acc2[1] = __builtin_elementwise_fma(w2, f, acc2[1]);
                f = f32x2{__uint_as_float(v.z << 16), __uint_as_float(v.z & 0xffff0000u)};
                acc2[2] = __builtin_elementwise_fma(w2, f, acc2[2]);
                f = f32x2{__uint_as_float(v.w << 16), __uint_as_float(v.w & 0xffff0000u)};
                acc2[3] = __builtin_elementwise_fma(w2, f, acc2[3]);
            }
        }
    };
    if (deg <= 128) run([&](int k) { return eps[wave][k]; });
    else           run([&](int k) { return ep[e0 + k]; });
#pragma unroll
    for (int off = 8; off <= 32; off <<= 1)
#pragma unroll
        for (int i = 0; i < 4; ++i) {
            acc2[i].x += __shfl_xor(acc2[i].x, off);
            acc2[i].y += __shfl_xor(acc2[i].y, off);
        }
    float dw = degw[node];
    float4 c0 = *(const float4*)(cvec + c * 8), c1 = *(const float4*)(cvec + c * 8 + 4);
    float4 r0 = *(const float4*)(r + c * 8),    r1 = *(const float4*)(r + c * 8 + 4);
    float v[8];
    v[0] = acc2[0].x + dw * c0.x + r0.x; v[1] = acc2[0].y + dw * c0.y + r0.y;
    v[2] = acc2[1].x + dw * c0.z + r0.z; v[3] = acc2[1].y + dw * c0.w + r0.w;
    v[4] = acc2[2].x + dw * c1.x + r1.x; v[5] = acc2[2].y + dw * c1.y + r1.y;
    v[6] = acc2[3].x + dw * c1.z + r1.z; v[7] = acc2[3].y + dw * c1.w + r1.w;
    float m = v[0];
#pragma unroll
    for (int i = 1; i < 8; ++i) m = fmaxf(m, v[i]);
#pragma unroll
    for (int off = 1; off <= 4; off <<= 1) m = fmaxf(m, __shfl_xor(m, off));
    float s = 0.f;
#pragma unroll
    for (int i = 0; i < 8; ++i) s += __expf(v[i] - m);
#pragma unroll
    for (int off = 1; off <= 4; off <<= 1) s += __shfl_xor(s, off);
    float ls = m + __logf(s);
    if (g == 0) {
        float4 o0 = make_float4(v[0] - ls, v[1] - ls, v[2] - ls, v[3] - ls);
        float4 o1 = make_float4(v[4] - ls, v[5] - ls, v[6] - ls, v[7] - ls);
        *(float4*)(out + (size_t)node * 64 + c * 8) = o0;
        *(float4*)(out + (size_t)node * 64 + c * 8 + 4) = o1;
    }
}

// ---------------------------------------------------------------------------

extern "C" void kernel_launch(void* const* d_in, const int* in_sizes, int n_in,
                              void* d_out, int out_size, void* d_ws, size_t ws_size,
                              hipStream_t stream) {
    const float* x   = (const float*)d_in[0];
    const int*   src = (const int*)d_in[1];
    const int*   dst = (const int*)d_in[2];
    const float* ew  = (const float*)d_in[3];
    const float* W1  = (const float*)d_in[4];
    const float* b1  = (const float*)d_in[5];
    const float* W2  = (const float*)d_in[6];
    const float* b2  = (const float*)d_in[7];
    const float* W3  = (const float*)d_in[8];
    const float* r   = (const float*)d_in[9];

    const int N = in_sizes[0] / 512;       // 100000
    const int E = in_sizes[1];             // 3200000
    const int NB = (N + 511) >> 9;         // dst buckets (196)
    const int buckcap = (((E / NB) * 5) / 4 + 255) & ~255;   // ~20480

    // ---- workspace layout ----
    char* ws = (char*)d_ws;
    __bf16* h1 = (__bf16*)ws;                            // N*256 bf16 @ 0
    char* regB = ws + (size_t)N * 512;
    unsigned char* h0f = (unsigned char*)regB;           // N*256 fp8
    __bf16* g3   = (__bf16*)regB;                        // reuse after spmm256
    __bf16* t1   = (__bf16*)(regB + (size_t)N * 128);
    float*  degw = (float*)(regB + (size_t)N * 256);
    char* regC = regB + (size_t)N * 512;
    __bf16* W1T  = (__bf16*)regC;                        // 512*256 bf16
    __bf16* W23T = (__bf16*)(regC + 512 * 256 * 2);      // 64*256 bf16
    float*  cvec = (float*)(regC + 512 * 256 * 2 + 64 * 256 * 2);
    char* regD = regC + 512 * 1024;
    int*  rp   = (int*)regD;                             // N+1 (pad to N+2)
    int*  gcnt = rp + (N + 2);                           // 256 (zeroed)
    int*  boff = gcnt + 256;                             // 256 (unused, kept)
    int2* ep   = (int2*)(boff + 256);                    // E pairs (8B aligned)
    int2* tb   = ep + E;                                 // NB*buckcap entries

    // ---- CSR build (2-phase bucket sort, no per-node global atomics) ----
    hipMemsetAsync(gcnt, 0, 256 * sizeof(int), stream);
    bucket_scatter<<<(E + TILE - 1) / TILE, 1024, 0, stream>>>(src, dst, ew,
                                                               gcnt, tb, E, buckcap);
    bucket_place<<<NB, 1024, 0, stream>>>(tb, gcnt, rp, ep, N, buckcap);

    // ---- precomputes ----
    cast_transpose<<<(512 * 256 + 255) / 256, 256, 0, stream>>>(W1, W1T, 512, 256);
    make_w23t<<<64, 256, 0, stream>>>(W2, W3, b2, W23T, cvec);

    // ---- layer 1 ----
    gemm1_fused<<<(N + 127) / 128, 512, 0, stream>>>(x, W1T, h0f, N);
    spmm256_fp8<<<(N + 3) / 4, 256, 0, stream>>>(h0f, rp, ep, b1, h1, N);

    // ---- fused layers 2+3 ----
    gemm2_mfma<<<(N + 127) / 128, 256, 0, stream>>>(h1, W23T, g3, N);
    spmm64_a<<<(N + 15) / 16, 1024, 0, stream>>>(g3, rp, ep, t1, degw, N);
    spmm64_b<<<(N + 15) / 16, 1024, 0, stream>>>(t1, rp, ep, degw, cvec, r, (float*)d_out, N);
}

// Round 6
// 654.754 us; speedup vs baseline: 1.0926x; 1.0493x over previous
//
#include <hip/hip_runtime.h>
#include <math.h>

// ---------------------------------------------------------------------------
// StatusGCN restructured:
//   h0 = fp8e4m3(x @ W1)              (MFMA, fp32 A cast in staging) [N,256]
//   h1 = bf16(relu(spmm(h0) + b1))                                  [N,256]
//   g3 = bf16(h1 @ (W2@W3))           (MFMA)                        [N,64]
//   t1 = bf16(spmm(g3)); degw = rowsum(w)                           [N,64]
//   out = log_softmax(spmm(t1) + degw*(b2@W3) + r)                  [N,64] f32
// Identities: spmm(X)@W == spmm(X@W);  spmm(X + 1*c) == spmm(X) + degw*c.
// CSR build: 2-phase bucket sort (pass1 LDS tile-sort -> bucket regions;
// pass2 per-bucket LDS histogram+scan writes rp and places exactly).
// r7: removed 3.2M per-node far-atomics: 849->729us.
// r8: 16-slot MLP in spmm256: 153->126us (BW 2.75->3.34 TB/s).
// r9: 1024-blocks+LDS-ep regressed spmm256 but helped spmm64_a/b (-19us).
// r10: unroll-8 regressed (clamped duplicate slots). FETCH pinned ~358MB
//     across 4 variants -> random-256B-gather ceiling; spmm256 done.
// r11: recombination: spmm256=r8-exact (126us, confirmed), spmm64=r9-exact,
//     folded gscan+make_c. 687us total, prediction matched.
// r12 (this round): the DAG's only parallelism is {CSR build} || {weights
// prep + gemm1}; streams/events forbidden under graph capture -> FAT
// KERNELS. A = transpose+w23t blocks then bucket_scatter blocks (1024thr,
// scatter body unchanged). B = bucket_place blocks (re-strided to 512thr)
// then gemm1 blocks (byte-identical 512thr body). All 978 B-blocks
// co-resident (30KB LDS union, 4 blk/CU) -> place's latency stalls filled
// by gemm1 MFMA waves. Serial ~140us est -> ~max chain ~100us, -2 launches.
// NOTE (r4 post-mortem): keep per-wave MFMA tile at 64x64 (acc[4][4]=64
// AGPR). Widen the BLOCK (more waves), never the wave.
// ---------------------------------------------------------------------------

typedef __bf16 bf16x8 __attribute__((ext_vector_type(8)));
typedef __bf16 bf16x4 __attribute__((ext_vector_type(4)));
typedef float f32x4 __attribute__((ext_vector_type(4)));
typedef float f32x2 __attribute__((ext_vector_type(2)));

#define TILE 2048
#define PRE_BLKS 144   // 128 transpose + 16 w23t

// ---------------- fat kernel A: weight prep + bucket_scatter ----------------

__global__ __launch_bounds__(1024) void prep_scatter(const int* __restrict__ src,
                                                     const int* __restrict__ dst,
                                                     const float* __restrict__ ew,
                                                     int* __restrict__ gcnt,
                                                     int2* __restrict__ tb,
                                                     int E, int buckcap,
                                                     const float* __restrict__ W1,
                                                     __bf16* __restrict__ W1T,
                                                     const float* __restrict__ W2,
                                                     const float* __restrict__ W3,
                                                     const float* __restrict__ b2,
                                                     __bf16* __restrict__ W23T,
                                                     float* __restrict__ cvec) {
    __shared__ __align__(16) char smem[21504];
    int bx = blockIdx.x;
    int tid = threadIdx.x;
    if (bx < 128) {                       // cast-transpose W1 (512x256), 131072 elems
        int i = bx * 1024 + tid;
        int k = i >> 8, n = i & 255;
        W1T[n * 512 + k] = (__bf16)W1[i];
        return;
    }
    if (bx < PRE_BLKS) {                  // W23T = (W2@W3)^T, cvec = b2@W3
        int idx = (bx - 128) * 1024 + tid;   // [0,16384)
        int n = idx & 63, k = idx >> 6;
        float s = 0.f;
        for (int j = 0; j < 64; ++j) s = fmaf(W2[k * 64 + j], W3[j * 64 + n], s);
        W23T[n * 256 + k] = (__bf16)s;
        if (idx < 64) {
            float t = 0.f;
            for (int j = 0; j < 64; ++j) t = fmaf(b2[j], W3[j * 64 + idx], t);
            cvec[idx] = t;
        }
        return;
    }
    // ---- bucket_scatter (body unchanged, smem carved) ----
    int* hist  = (int*)smem;                                // 256
    int* hscan = hist + 256;                                // 256
    int* gbase = hscan + 256;                               // 256
    int2* stage = (int2*)(gbase + 256);                     // 2048 int2
    unsigned char* sbuck = (unsigned char*)(stage + TILE);  // 2048
    int e0 = (bx - PRE_BLKS) * TILE;
    int tilecnt = min(TILE, E - e0);
    if (tid < 256) hist[tid] = 0;
    __syncthreads();
    int myb[2], myr[2], key[2], mw[2];
#pragma unroll
    for (int u = 0; u < 2; ++u) {
        int e = e0 + u * 1024 + tid;
        myb[u] = -1;
        if (e < E) {
            int d = dst[e];
            int b = d >> 9;
            key[u] = (src[e] << 9) | (d & 511);
            mw[u] = __float_as_int(ew[e]);
            myb[u] = b;
            myr[u] = atomicAdd(&hist[b], 1);   // rank within (tile, bucket)
        }
    }
    __syncthreads();
    if (tid < 256) {
        hscan[tid] = hist[tid];
        gbase[tid] = (hist[tid] > 0) ? atomicAdd(&gcnt[tid], hist[tid]) : 0;
    }
    __syncthreads();
    for (int off = 1; off < 256; off <<= 1) {    // inclusive scan of hist
        int t = 0;
        if (tid < 256 && tid >= off) t = hscan[tid - off];
        __syncthreads();
        if (tid < 256) hscan[tid] += t;
        __syncthreads();
    }
#pragma unroll
    for (int u = 0; u < 2; ++u) {
        if (myb[u] >= 0) {
            int b = myb[u];
            int p = hscan[b] - hist[b] + myr[u];
            stage[p] = make_int2(key[u], mw[u]);
            sbuck[p] = (unsigned char)b;
        }
    }
    __syncthreads();
    for (int i = tid; i < tilecnt; i += 1024) {  // bursty, run-contiguous writes
        int2 ent = stage[i];
        int b = sbuck[i];
        int exc = hscan[b] - hist[b];
        tb[(size_t)b * buckcap + gbase[b] + (i - exc)] = ent;
    }
}

// ------------- fat kernel B: bucket_place + gemm1 (co-resident) -------------
// gemm1: h0_fp8[M,256] = bf16(A_f32[M,512]) @ W1T; place: rp/ep from tb.

__global__ __launch_bounds__(512) void place_gemm1(const int2* __restrict__ tb,
                                                   const int* __restrict__ gcnt,
                                                   int* __restrict__ rp,
                                                   int2* __restrict__ ep,
                                                   int N, int buckcap,
                                                   const float* __restrict__ A,
                                                   const __bf16* __restrict__ BT,
                                                   unsigned char* __restrict__ C) {
    __shared__ __align__(16) char smem[30720];
    const int tid = threadIdx.x;
    const int bx = blockIdx.x;
    const int NBp = (N + 511) >> 9;
    if (bx < NBp) {
        // ---- bucket_place (re-strided to 512 threads) ----
        int* h = (int*)smem;          // 512
        int* cursor = h + 512;        // 512
        int* gs = cursor + 512;       // 256
        int b = bx;
        int base = b << 9;
        int nn = min(512, N - base);
        h[tid] = 0;
        if (tid < 256) gs[tid] = gcnt[tid];
        __syncthreads();
        for (int off = 1; off < 256; off <<= 1) {    // inclusive scan of gcnt
            int t = (tid < 256 && tid >= off) ? gs[tid - off] : 0;
            __syncthreads();
            if (tid < 256) gs[tid] += t;
            __syncthreads();
        }
        int cb = gcnt[b];
        int bo = gs[b] - cb;                          // exclusive bucket base
        if (b == 0 && tid == 0) rp[N] = gs[255];      // total = E
        const int2* tbb = tb + (size_t)b * buckcap;
        for (int i = tid; i < cb; i += 512)
            atomicAdd(&h[((unsigned)tbb[i].x) & 511], 1);
        __syncthreads();
        cursor[tid] = h[tid];
        __syncthreads();
        for (int off = 1; off < 512; off <<= 1) {    // inclusive scan
            int t = (tid >= off) ? cursor[tid - off] : 0;
            __syncthreads();
            cursor[tid] += t;
            __syncthreads();
        }
        int excl = cursor[tid] - h[tid] + bo;        // exclusive + bucket base
        cursor[tid] = excl;
        if (tid < nn) rp[base + tid] = excl;
        __syncthreads();
        for (int i = tid; i < cb; i += 512) {        // 2nd pass: L2-warm region
            int2 e = tbb[i];
            int pos = atomicAdd(&cursor[((unsigned)e.x) & 511], 1);
            ep[pos] = make_int2((int)(((unsigned)e.x) >> 9), e.y);
        }
        return;
    }
    // ---- gemm1 (byte-identical 512-thread body, smem carved) ----
    const int K = 512, M = N;
    __bf16* As = (__bf16*)smem;          // 128*40
    __bf16* Bs = As + 128 * 40;          // 256*40
    const int wave = tid >> 6, lane = tid & 63;
    const int wm = wave >> 2, wn = wave & 3;
    const int quad = lane >> 4, l16 = lane & 15;
    const int bm = (bx - NBp) * 128;
    f32x4 acc[4][4] = {};
    for (int k0 = 0; k0 < K; k0 += 32) {
#pragma unroll
        for (int it = 0; it < 2; ++it) {
            int idx = tid + it * 512;
            int row = idx >> 3, ch = idx & 7;
            int gm = bm + row;
            float4 v = (gm < M) ? *(const float4*)(A + (size_t)gm * K + k0 + ch * 4)
                                : make_float4(0.f, 0.f, 0.f, 0.f);
            bf16x4 o;
            o[0] = (__bf16)v.x; o[1] = (__bf16)v.y; o[2] = (__bf16)v.z; o[3] = (__bf16)v.w;
            *(bf16x4*)(As + row * 40 + ch * 4) = o;
        }
#pragma unroll
        for (int it = 0; it < 2; ++it) {
            int idx = tid + it * 512;
            int row = idx >> 2, ch = idx & 3;
            *(bf16x8*)(Bs + row * 40 + ch * 8) =
                *(const bf16x8*)(BT + (size_t)row * K + k0 + ch * 8);
        }
        __syncthreads();
        bf16x8 a[4], b[4];
#pragma unroll
        for (int i = 0; i < 4; ++i)
            a[i] = *(bf16x8*)(As + (wm * 64 + i * 16 + l16) * 40 + quad * 8);
#pragma unroll
        for (int j = 0; j < 4; ++j)
            b[j] = *(bf16x8*)(Bs + (wn * 64 + j * 16 + l16) * 40 + quad * 8);
#pragma unroll
        for (int i = 0; i < 4; ++i)
#pragma unroll
            for (int j = 0; j < 4; ++j)
                acc[i][j] = __builtin_amdgcn_mfma_f32_16x16x32_bf16(a[i], b[j], acc[i][j], 0, 0, 0);
        __syncthreads();
    }
#pragma unroll
    for (int i = 0; i < 4; ++i)
#pragma unroll
        for (int j = 0; j < 4; ++j)
#pragma unroll
            for (int rr = 0; rr < 4; ++rr) {
                int row = bm + wm * 64 + i * 16 + quad * 4 + rr;
                int col = wn * 64 + j * 16 + l16;
                if (row < M) {
                    unsigned int p = __builtin_amdgcn_cvt_pk_fp8_f32(acc[i][j][rr],
                                                                     acc[i][j][rr], 0, false);
                    C[(size_t)row * 256 + col] = (unsigned char)(p & 0xff);
                }
            }
}

// ---------------- MFMA GEMM 2: C[M,64] = A[M,256] @ B[256,64] ---------------

__global__ __launch_bounds__(256) void gemm2_mfma(const __bf16* __restrict__ A,
                                                  const __bf16* __restrict__ BT,
                                                  __bf16* __restrict__ C, int M) {
    const int K = 256, Nn = 64;
    __shared__ __align__(16) __bf16 Bs[64 * 264];
    __shared__ __align__(16) __bf16 As[128 * 40];
    const int tid = threadIdx.x;
    const int wave = tid >> 6, lane = tid & 63;
    const int quad = lane >> 4, l16 = lane & 15;
    const int bm = blockIdx.x * 128;
#pragma unroll
    for (int it = 0; it < 8; ++it) {
        int e = tid + it * 256;
        int row = e >> 5, ch = e & 31;
        *(bf16x8*)(Bs + row * 264 + ch * 8) = *(const bf16x8*)(BT + row * 256 + ch * 8);
    }
    f32x4 acc[2][4] = {};
    for (int k0 = 0; k0 < K; k0 += 32) {
#pragma unroll
        for (int it = 0; it < 2; ++it) {
            int e = tid + it * 256;
            int row = e >> 2, ch = e & 3;
            int gm = bm + row;
            bf16x8 v = {};
            if (gm < M) v = *(const bf16x8*)(A + (size_t)gm * K + k0 + ch * 8);
            *(bf16x8*)(As + row * 40 + ch * 8) = v;
        }
        __syncthreads();
        bf16x8 a[2], b[4];
#pragma unroll
        for (int i = 0; i < 2; ++i)
            a[i] = *(bf16x8*)(As + (wave * 32 + i * 16 + l16) * 40 + quad * 8);
#pragma unroll
        for (int j = 0; j < 4; ++j)
            b[j] = *(bf16x8*)(Bs + (j * 16 + l16) * 264 + k0 + quad * 8);
#pragma unroll
        for (int i = 0; i < 2; ++i)
#pragma unroll
            for (int j = 0; j < 4; ++j)
                acc[i][j] = __builtin_amdgcn_mfma_f32_16x16x32_bf16(a[i], b[j], acc[i][j], 0, 0, 0);
        __syncthreads();
    }
#pragma unroll
    for (int i = 0; i < 2; ++i)
#pragma unroll
        for (int j = 0; j < 4; ++j)
#pragma unroll
            for (int rr = 0; rr < 4; ++rr) {
                int row = bm + wave * 32 + i * 16 + quad * 4 + rr;
                int col = j * 16 + l16;
                if (row < M) C[(size_t)row * Nn + col] = (__bf16)acc[i][j][rr];
            }
}

// ---------------- pull-mode SpMM ----------------

// r8-exact: 4-wave blocks, direct ep stream, 16 slots/iter, 16 lanes x
// uint4 = coalesced 256B row. Proven 126us (pattern roofline).
__global__ __launch_bounds__(256) void spmm256_fp8(const unsigned char* __restrict__ h,
                                                   const int* __restrict__ rp,
                                                   const int2* __restrict__ ep,
                                                   const float* __restrict__ bias,
                                                   __bf16* __restrict__ out, int n) {
    int node = blockIdx.x * 4 + (threadIdx.x >> 6);
    if (node >= n) return;
    int lane = threadIdx.x & 63;
    int q = lane >> 4, c = lane & 15;
    int e0 = rp[node], e1 = rp[node + 1];
    float acc[16] = {};
    for (int e = e0; e < e1; e += 16) {
#pragma unroll
        for (int u = 0; u < 4; ++u) {
            int ee = e + u * 4 + q;
            int cl = min(ee, e1 - 1);
            int2 p = ep[cl];
            float w = (ee < e1) ? __int_as_float(p.y) : 0.f;
            uint4 v = *(const uint4*)(h + (size_t)p.x * 256 + c * 16);
            f32x2 f;
            f = __builtin_amdgcn_cvt_pk_f32_fp8(v.x, false);
            acc[0] = fmaf(w, f.x, acc[0]);  acc[1] = fmaf(w, f.y, acc[1]);
            f = __builtin_amdgcn_cvt_pk_f32_fp8(v.x, true);
            acc[2] = fmaf(w, f.x, acc[2]);  acc[3] = fmaf(w, f.y, acc[3]);
            f = __builtin_amdgcn_cvt_pk_f32_fp8(v.y, false);
            acc[4] = fmaf(w, f.x, acc[4]);  acc[5] = fmaf(w, f.y, acc[5]);
            f = __builtin_amdgcn_cvt_pk_f32_fp8(v.y, true);
            acc[6] = fmaf(w, f.x, acc[6]);  acc[7] = fmaf(w, f.y, acc[7]);
            f = __builtin_amdgcn_cvt_pk_f32_fp8(v.z, false);
            acc[8] = fmaf(w, f.x, acc[8]);  acc[9] = fmaf(w, f.y, acc[9]);
            f = __builtin_amdgcn_cvt_pk_f32_fp8(v.z, true);
            acc[10] = fmaf(w, f.x, acc[10]); acc[11] = fmaf(w, f.y, acc[11]);
            f = __builtin_amdgcn_cvt_pk_f32_fp8(v.w, false);
            acc[12] = fmaf(w, f.x, acc[12]); acc[13] = fmaf(w, f.y, acc[13]);
            f = __builtin_amdgcn_cvt_pk_f32_fp8(v.w, true);
            acc[14] = fmaf(w, f.x, acc[14]); acc[15] = fmaf(w, f.y, acc[15]);
        }
    }
#pragma unroll
    for (int off = 16; off <= 32; off <<= 1)
#pragma unroll
        for (int i = 0; i < 16; ++i) acc[i] += __shfl_xor(acc[i], off);
    if (q == 0) {
        float4 b0 = *(const float4*)(bias + c * 16);
        float4 b1 = *(const float4*)(bias + c * 16 + 4);
        float4 b2 = *(const float4*)(bias + c * 16 + 8);
        float4 b3 = *(const float4*)(bias + c * 16 + 12);
        bf16x8 o0, o1;
        o0[0] = (__bf16)fmaxf(acc[0] + b0.x, 0.f);
        o0[1] = (__bf16)fmaxf(acc[1] + b0.y, 0.f);
        o0[2] = (__bf16)fmaxf(acc[2] + b0.z, 0.f);
        o0[3] = (__bf16)fmaxf(acc[3] + b0.w, 0.f);
        o0[4] = (__bf16)fmaxf(acc[4] + b1.x, 0.f);
        o0[5] = (__bf16)fmaxf(acc[5] + b1.y, 0.f);
        o0[6] = (__bf16)fmaxf(acc[6] + b1.z, 0.f);
        o0[7] = (__bf16)fmaxf(acc[7] + b1.w, 0.f);
        o1[0] = (__bf16)fmaxf(acc[8] + b2.x, 0.f);
        o1[1] = (__bf16)fmaxf(acc[9] + b2.y, 0.f);
        o1[2] = (__bf16)fmaxf(acc[10] + b2.z, 0.f);
        o1[3] = (__bf16)fmaxf(acc[11] + b2.w, 0.f);
        o1[4] = (__bf16)fmaxf(acc[12] + b3.x, 0.f);
        o1[5] = (__bf16)fmaxf(acc[13] + b3.y, 0.f);
        o1[6] = (__bf16)fmaxf(acc[14] + b3.z, 0.f);
        o1[7] = (__bf16)fmaxf(acc[15] + b3.w, 0.f);
        *(bf16x8*)(out + (size_t)node * 256 + c * 16) = o0;
        *(bf16x8*)(out + (size_t)node * 256 + c * 16 + 8) = o1;
    }
}

// r9-exact: 1024-thread blocks, LDS-staged ep (entry shared by 8 lanes ->
// broadcast amortizes), packed f32x2 FMA. Proven -19us vs r8 baseline.
__global__ __launch_bounds__(1024) void spmm64_a(const __bf16* __restrict__ h,
                                                 const int* __restrict__ rp,
                                                 const int2* __restrict__ ep,
                                                 __bf16* __restrict__ out,
                                                 float* __restrict__ degw, int n) {
    __shared__ int2 eps[16][128];
    int wave = threadIdx.x >> 6;
    int node = blockIdx.x * 16 + wave;
    if (node >= n) return;
    int lane = threadIdx.x & 63;
    int g = lane >> 3, c = lane & 7;
    int e0 = rp[node], e1 = rp[node + 1];
    int deg = e1 - e0;
    for (int k = lane; k < min(deg, 128); k += 64) eps[wave][k] = ep[e0 + k];
    f32x2 acc2[4] = {};
    float ws = 0.f;
    auto run = [&](auto fetch) {
        for (int e = 0; e < deg; e += 32) {
#pragma unroll
            for (int u = 0; u < 4; ++u) {
                int s = e + u * 8 + g;
                int k = min(s, deg - 1);
                int2 p = fetch(k);
                float wv = (s < deg) ? __int_as_float(p.y) : 0.f;
                f32x2 w2 = {wv, wv};
                uint4 v = *(const uint4*)(h + (size_t)p.x * 64 + c * 8);
                f32x2 f;
                f = f32x2{__uint_as_float(v.x << 16), __uint_as_float(v.x & 0xffff0000u)};
                acc2[0] = __builtin_elementwise_fma(w2, f, acc2[0]);
                f = f32x2{__uint_as_float(v.y << 16), __uint_as_float(v.y & 0xffff0000u)};
                acc2[1] = __builtin_elementwise_fma(w2, f, acc2[1]);
                f = f32x2{__uint_as_float(v.z << 16), __uint_as_float(v.z & 0xffff0000u)};
                acc2[2] = __builtin_elementwise_fma(w2, f, acc2[2]);
                f = f32x2{__uint_as_float(v.w << 16), __uint_as_float(v.w & 0xffff0000u)};
                acc2[3] = __builtin_elementwise_fma(w2, f, acc2[3]);
                ws += wv;
            }
        }
    };
    if (deg <= 128) run([&](int k) { return eps[wave][k]; });
    else           run([&](int k) { return ep[e0 + k]; });
#pragma unroll
    for (int off = 8; off <= 32; off <<= 1) {
        ws += __shfl_xor(ws, off);
#pragma unroll
        for (int i = 0; i < 4; ++i) {
            acc2[i].x += __shfl_xor(acc2[i].x, off);
            acc2[i].y += __shfl_xor(acc2[i].y, off);
        }
    }
    if (lane == 0) degw[node] = ws;
    if (g == 0) {
        bf16x8 o;
#pragma unroll
        for (int i = 0; i < 4; ++i) {
            o[2 * i] = (__bf16)acc2[i].x;
            o[2 * i + 1] = (__bf16)acc2[i].y;
        }
        *(bf16x8*)(out + (size_t)node * 64 + c * 8) = o;
    }
}

__global__ __launch_bounds__(1024) void spmm64_b(const __bf16* __restrict__ h,
                                                 const int* __restrict__ rp,
                                                 const int2* __restrict__ ep,
                                                 const float* __restrict__ degw,
                                                 const float* __restrict__ cvec,
                                                 const float* __restrict__ r,
                                                 float* __restrict__ out, int n) {
    __shared__ int2 eps[16][128];
    int wave = threadIdx.x >> 6;
    int node = blockIdx.x * 16 + wave;
    if (node >= n) return;
    int lane = threadIdx.x & 63;
    int g = lane >> 3, c = lane & 7;
    int e0 = rp[node], e1 = rp[node + 1];
    int deg = e1 - e0;
    for (int k = lane; k < min(deg, 128); k += 64) eps[wave][k] = ep[e0 + k];
    f32x2 acc2[4] = {};
    auto run = [&](auto fetch) {
        for (int e = 0; e < deg; e += 32) {
#pragma unroll
            for (int u = 0; u < 4; ++u) {
                int s = e + u * 8 + g;
                int k = min(s, deg - 1);
                int2 p = fetch(k);
                float wv = (s < deg) ? __int_as_float(p.y) : 0.f;
                f32x2 w2 = {wv, wv};
                uint4 v = *(const uint4*)(h + (size_t)p.x * 64 + c * 8);
                f32x2 f;
                f = f32x2{__uint_as_float(v.x << 16), __uint_as_float(v.x & 0xffff0000u)};
                acc2[0] = __builtin_elementwise_fma(w2, f, acc2[0]);
                f = f32x2{__uint_as_float(v.y << 16), __uint_as_float(v.y & 0xffff0000u)};
                acc2[1] = __builtin_elementwise_fma(w2, f, acc2[1]);
                f = f32x2{__uint_as_float(v.z << 16), __uint_as_float(v.z & 0xffff0000u)};
                acc2[2] = __builtin_elementwise_fma(w2, f, acc2[2]);
                f = f32x2{__uint_as_float(v.w << 16), __uint_as_float(v.w & 0xffff0000u)};
                acc2[3] = __builtin_elementwise_fma(w2, f, acc2[3]);
            }
        }
    };
    if (deg <= 128) run([&](int k) { return eps[wave][k]; });
    else           run([&](int k) { return ep[e0 + k]; });
#pragma unroll
    for (int off = 8; off <= 32; off <<= 1)
#pragma unroll
        for (int i = 0; i < 4; ++i) {
            acc2[i].x += __shfl_xor(acc2[i].x, off);
            acc2[i].y += __shfl_xor(acc2[i].y, off);
        }
    float dw = degw[node];
    float4 c0 = *(const float4*)(cvec + c * 8), c1 = *(const float4*)(cvec + c * 8 + 4);
    float4 r0 = *(const float4*)(r + c * 8),    r1 = *(const float4*)(r + c * 8 + 4);
    float v[8];
    v[0] = acc2[0].x + dw * c0.x + r0.x; v[1] = acc2[0].y + dw * c0.y + r0.y;
    v[2] = acc2[1].x + dw * c0.z + r0.z; v[3] = acc2[1].y + dw * c0.w + r0.w;
    v[4] = acc2[2].x + dw * c1.x + r1.x; v[5] = acc2[2].y + dw * c1.y + r1.y;
    v[6] = acc2[3].x + dw * c1.z + r1.z; v[7] = acc2[3].y + dw * c1.w + r1.w;
    float m = v[0];
#pragma unroll
    for (int i = 1; i < 8; ++i) m = fmaxf(m, v[i]);
#pragma unroll
    for (int off = 1; off <= 4; off <<= 1) m = fmaxf(m, __shfl_xor(m, off));
    float s = 0.f;
#pragma unroll
    for (int i = 0; i < 8; ++i) s += __expf(v[i] - m);
#pragma unroll
    for (int off = 1; off <= 4; off <<= 1) s += __shfl_xor(s, off);
    float ls = m + __logf(s);
    if (g == 0) {
        float4 o0 = make_float4(v[0] - ls, v[1] - ls, v[2] - ls, v[3] - ls);
        float4 o1 = make_float4(v[4] - ls, v[5] - ls, v[6] - ls, v[7] - ls);
        *(float4*)(out + (size_t)node * 64 + c * 8) = o0;
        *(float4*)(out + (size_t)node * 64 + c * 8 + 4) = o1;
    }
}

// ---------------------------------------------------------------------------

extern "C" void kernel_launch(void* const* d_in, const int* in_sizes, int n_in,
                              void* d_out, int out_size, void* d_ws, size_t ws_size,
                              hipStream_t stream) {
    const float* x   = (const float*)d_in[0];
    const int*   src = (const int*)d_in[1];
    const int*   dst = (const int*)d_in[2];
    const float* ew  = (const float*)d_in[3];
    const float* W1  = (const float*)d_in[4];
    const float* b1  = (const float*)d_in[5];
    const float* W2  = (const float*)d_in[6];
    const float* b2  = (const float*)d_in[7];
    const float* W3  = (const float*)d_in[8];
    const float* r   = (const float*)d_in[9];

    const int N = in_sizes[0] / 512;       // 100000
    const int E = in_sizes[1];             // 3200000
    const int NB = (N + 511) >> 9;         // dst buckets (196)
    const int buckcap = (((E / NB) * 5) / 4 + 255) & ~255;   // ~20480

    // ---- workspace layout ----
    char* ws = (char*)d_ws;
    __bf16* h1 = (__bf16*)ws;                            // N*256 bf16 @ 0
    char* regB = ws + (size_t)N * 512;
    unsigned char* h0f = (unsigned char*)regB;           // N*256 fp8
    __bf16* g3   = (__bf16*)regB;                        // reuse after spmm256
    __bf16* t1   = (__bf16*)(regB + (size_t)N * 128);
    float*  degw = (float*)(regB + (size_t)N * 256);
    char* regC = regB + (size_t)N * 512;
    __bf16* W1T  = (__bf16*)regC;                        // 512*256 bf16
    __bf16* W23T = (__bf16*)(regC + 512 * 256 * 2);      // 64*256 bf16
    float*  cvec = (float*)(regC + 512 * 256 * 2 + 64 * 256 * 2);
    char* regD = regC + 512 * 1024;
    int*  rp   = (int*)regD;                             // N+1 (pad to N+2)
    int*  gcnt = rp + (N + 2);                           // 256 (zeroed)
    int*  boff = gcnt + 256;                             // 256 (unused, kept)
    int2* ep   = (int2*)(boff + 256);                    // E pairs (8B aligned)
    int2* tb   = ep + E;                                 // NB*buckcap entries

    // ---- fat kernel A: weight prep || bucket_scatter ----
    hipMemsetAsync(gcnt, 0, 256 * sizeof(int), stream);
    prep_scatter<<<PRE_BLKS + (E + TILE - 1) / TILE, 1024, 0, stream>>>(
        src, dst, ew, gcnt, tb, E, buckcap, W1, W1T, W2, W3, b2, W23T, cvec);

    // ---- fat kernel B: bucket_place || gemm1 ----
    place_gemm1<<<NB + (N + 127) / 128, 512, 0, stream>>>(
        tb, gcnt, rp, ep, N, buckcap, x, W1T, h0f);

    // ---- layer 1 aggregation ----
    spmm256_fp8<<<(N + 3) / 4, 256, 0, stream>>>(h0f, rp, ep, b1, h1, N);

    // ---- fused layers 2+3 ----
    gemm2_mfma<<<(N + 127) / 128, 256, 0, stream>>>(h1, W23T, g3, N);
    spmm64_a<<<(N + 15) / 16, 1024, 0, stream>>>(g3, rp, ep, t1, degw, N);
    spmm64_b<<<(N + 15) / 16, 1024, 0, stream>>>(t1, rp, ep, degw, cvec, r, (float*)d_out, N);
}